// Round 2
// baseline (1930.958 us; speedup 1.0000x reference)
//
#include <hip/hip_runtime.h>

#define E_EDGES 65536
#define N_NODES 4096

// ---- workspace layout (float offsets) ----
// [0,678)   w3j tensors, [678] C2, [679] C3  (reserve 1024)
#define WS_W     1024                       // E*64   w = x@Ww/8
#define WS_Y     (WS_W + E_EDGES*64)        // E*16   Y
#define WS_CNT   (WS_Y + E_EDGES*16)        // 4096 int
#define WS_OFF   (WS_CNT + N_NODES)         // 4096 int
#define WS_CUR   (WS_OFF + N_NODES)         // 4096 int
#define WS_SORT  (WS_CUR + N_NODES)         // E int
#define WS_A     (WS_SORT + E_EDGES)        // N*1024  node accumulator (eps folded)
// high-water: (WS_A + 4096*1024) floats = 9,516,032 floats ~= 38.1 MB

// key order: (0,0,0),(1,1,0),(2,2,0),(0,1,1),(1,0,1),(1,2,1),(2,1,1),(3,2,1),
//            (0,2,2),(1,1,2),(2,0,2),(2,2,2),(3,1,2),(2,1,3)
__constant__ int gK_L1[14] = {0,1,2,0,1,1,2,3,0,1,2,2,3,2};
__constant__ int gK_L2[14] = {0,1,2,1,0,2,1,2,2,1,0,2,1,1};
__constant__ int gK_L3[14] = {0,0,0,1,1,1,1,1,2,2,2,2,2,3};
__constant__ int gK_OFF[14]= {0,1,10,35,44,53,98,143,248,273,318,343,468,573};
__constant__ double gFact[8] = {1.,1.,2.,6.,24.,120.,720.,5040.};

// w3j offsets (compile-time)
#define O_W000 0
#define O_W110 1
#define O_W220 10
#define O_W011 35
#define O_W101 44
#define O_W121 53
#define O_W211 98
#define O_W321 143
#define O_W022 248
#define O_W112 273
#define O_W202 318
#define O_W222 343
#define O_W312 468
#define O_W213 573

__device__ double su2_cg(int j1,int j2,int j3,int m1,int m2,int m3){
  if (m3 != m1+m2) return 0.0;
  double pref = sqrt((double)(2*j3+1)*gFact[j3+j1-j2]*gFact[j3-j1+j2]*gFact[j1+j2-j3]/gFact[j1+j2+j3+1]);
  pref *= sqrt(gFact[j3+m3]*gFact[j3-m3]*gFact[j1-m1]*gFact[j1+m1]*gFact[j2-m2]*gFact[j2+m2]);
  double s=0.0;
  for(int k=0;k<=j1+j2-j3;k++){
    int d1=j1+j2-j3-k, d2=j1-m1-k, d3=j2+m2-k, d4=j3-j2+m1+k, d5=j3-j1-m2+k;
    if(d1<0||d2<0||d3<0||d4<0||d5<0) continue;
    double den=gFact[k]*gFact[d1]*gFact[d2]*gFact[d3]*gFact[d4]*gFact[d5];
    s += (k&1)? (-1.0/den) : (1.0/den);
  }
  return pref*s;
}

__device__ void fill_qmat(int l, double2* q){  // 7x7 row-major, rows=m-basis, cols=real-basis
  for(int i=0;i<49;i++){ q[i].x=0.0; q[i].y=0.0; }
  const double is2 = 0.7071067811865475244;
  for(int m=-l;m<0;m++){
    q[(l+m)*7+(l-m)].x = is2;     // q[l+m, l+|m|] = 1/sqrt2
    q[(l+m)*7+(l+m)].y = -is2;    // q[l+m, l-|m|] = -1j/sqrt2
  }
  q[l*7+l].x = 1.0;
  for(int m=1;m<=l;m++){
    double sg = (m&1)? -1.0 : 1.0;
    q[(l+m)*7+(l+m)].x = sg*is2;
    q[(l+m)*7+(l-m)].y = sg*is2;
  }
  double pr, pi;  // (-i)^l
  switch(l&3){ case 0: pr=1;pi=0;break; case 1: pr=0;pi=-1;break; case 2: pr=-1;pi=0;break; default: pr=0;pi=1;break; }
  for(int i=0;i<49;i++){
    double a=q[i].x, b=q[i].y;
    q[i].x = a*pr - b*pi;
    q[i].y = a*pi + b*pr;
  }
}

__global__ __launch_bounds__(128) void k_w3j(float* __restrict__ ws){
  __shared__ double2 q1[49], q2[49], q3[49];
  __shared__ double C[125], Cr[125];
  __shared__ double red[128];
  int bid = blockIdx.x, t = threadIdx.x;
  int l1=gK_L1[bid], l2=gK_L2[bid], l3=gK_L3[bid];
  int n1=2*l1+1, n2=2*l2+1, n3=2*l3+1, ntot=n1*n2*n3;
  if(t==0){
    fill_qmat(l1,q1); fill_qmat(l2,q2); fill_qmat(l3,q3);
    for(int i=0;i<49;i++) q3[i].y = -q3[i].y;   // conj
  }
  __syncthreads();
  for(int idx=t; idx<ntot; idx+=128){
    int a = idx/(n2*n3), r=idx%(n2*n3), b=r/n3, c=r%n3;
    C[idx] = su2_cg(l1,l2,l3, a-l1, b-l2, c-l3);
  }
  __syncthreads();
  for(int idx=t; idx<ntot; idx+=128){
    int i = idx/(n2*n3), r=idx%(n2*n3), j=r/n3, k=r%n3;
    double ar=0.0;
    for(int a=0;a<n1;a++) for(int b=0;b<n2;b++){
      double2 qa=q1[a*7+i], qb=q2[b*7+j];
      double pr = qa.x*qb.x - qa.y*qb.y;
      double pi = qa.x*qb.y + qa.y*qb.x;
      for(int c=0;c<n3;c++){
        double2 qc=q3[c*7+k];
        double tr = pr*qc.x - pi*qc.y;
        ar += tr*C[(a*n2+b)*n3+c];
      }
    }
    Cr[idx]=ar;
  }
  __syncthreads();
  double ss=0.0;
  for(int idx=t; idx<ntot; idx+=128) ss += Cr[idx]*Cr[idx];
  red[t]=ss; __syncthreads();
  for(int st=64; st>0; st>>=1){ if(t<st) red[t]+=red[t+st]; __syncthreads(); }
  double inv = 1.0/sqrt(red[0]);
  for(int idx=t; idx<ntot; idx+=128) ws[gK_OFF[bid]+idx] = (float)(Cr[idx]*inv);
}

__global__ void k_c2c3(float* __restrict__ ws){
  const float* w112 = ws + O_W112;
  const float* w213 = ws + O_W213;
  double u0=0.3, u1=-0.4, u2=sqrt(0.75);
  double s3=sqrt(3.0);
  double y1[3]={s3*u0, s3*u1, s3*u2};
  double y2r[5]={0,0,0,0,0};
  for(int i=0;i<3;i++) for(int j=0;j<3;j++) for(int k=0;k<5;k++)
    y2r[k] += y1[i]*y1[j]*(double)w112[(i*3+j)*5+k];
  double nn=0; for(int k=0;k<5;k++) nn += y2r[k]*y2r[k];
  double c2 = sqrt(5.0)/sqrt(nn);
  double y2[5]; for(int k=0;k<5;k++) y2[k]=c2*y2r[k];
  double y3r[7]={0,0,0,0,0,0,0};
  for(int i=0;i<5;i++) for(int j=0;j<3;j++) for(int n=0;n<7;n++)
    y3r[n] += y2[i]*y1[j]*(double)w213[(i*3+j)*7+n];
  nn=0; for(int n=0;n<7;n++) nn += y3r[n]*y3r[n];
  double c3 = sqrt(7.0)/sqrt(nn);
  ws[678]=(float)c2; ws[679]=(float)c3;
}

__global__ void k_zero(int* __restrict__ cnt){
  int i = blockIdx.x*256 + threadIdx.x;
  if(i < N_NODES) cnt[i]=0;
}
__global__ void k_count(const int* __restrict__ senders, int* __restrict__ cnt){
  int e = blockIdx.x*256 + threadIdx.x;
  if(e < E_EDGES) atomicAdd(&cnt[senders[e]], 1);
}
__global__ __launch_bounds__(1024) void k_scan(const int* __restrict__ cnt, int* __restrict__ off, int* __restrict__ cur){
  __shared__ int part[1024];
  int t = threadIdx.x;
  int c0=cnt[4*t], c1=cnt[4*t+1], c2=cnt[4*t+2], c3=cnt[4*t+3];
  int l0=0, l1=c0, l2=c0+c1, l3=c0+c1+c2;
  int sum=l3+c3;
  part[t]=sum; __syncthreads();
  for(int st=1; st<1024; st<<=1){
    int v = part[t];
    int add = (t>=st)? part[t-st] : 0;
    __syncthreads();
    part[t] = v + add;
    __syncthreads();
  }
  int pref = (t>0)? part[t-1] : 0;
  off[4*t]=pref+l0; off[4*t+1]=pref+l1; off[4*t+2]=pref+l2; off[4*t+3]=pref+l3;
  cur[4*t]=pref+l0; cur[4*t+1]=pref+l1; cur[4*t+2]=pref+l2; cur[4*t+3]=pref+l3;
}
__global__ void k_scatter(const int* __restrict__ senders, int* __restrict__ cur, int* __restrict__ sorted){
  int e = blockIdx.x*256 + threadIdx.x;
  if(e < E_EDGES){
    int pos = atomicAdd(&cur[senders[e]], 1);
    sorted[pos] = e;
  }
}

// per edge: w = x@Ww/8 (lane=mul), Y[16] spherical harmonics
__global__ __launch_bounds__(256) void k_edge_pre(
    const float* __restrict__ vectors, const float* __restrict__ x,
    const float* __restrict__ Ww, float* __restrict__ ws){
  int wv = threadIdx.x >> 6, lane = threadIdx.x & 63;
  int e = blockIdx.x*4 + wv;
  const float* w112 = ws + O_W112;
  const float* w213 = ws + O_W213;
  float C2v = ws[678], C3v = ws[679];
  float v0=vectors[e*3], v1=vectors[e*3+1], v2=vectors[e*3+2];
  float len = sqrtf(v0*v0+v1*v1+v2*v2);
  float inv = 1.0f/(len + 1e-12f);
  float s3 = 1.7320508075688772f;
  float y1v[3] = { s3*v0*inv, s3*v1*inv, s3*v2*inv };
  float y2[5];
  #pragma unroll
  for(int k=0;k<5;k++){
    float a=0.f;
    #pragma unroll
    for(int i=0;i<3;i++)
      #pragma unroll
      for(int j=0;j<3;j++) a += y1v[i]*y1v[j]*w112[(i*3+j)*5+k];
    y2[k]=C2v*a;
  }
  float y3[7];
  #pragma unroll
  for(int n=0;n<7;n++){
    float a=0.f;
    #pragma unroll
    for(int i=0;i<5;i++)
      #pragma unroll
      for(int j=0;j<3;j++) a += y2[i]*y1v[j]*w213[(i*3+j)*7+n];
    y3[n]=C3v*a;
  }
  // w
  float acc=0.f;
  for(int k=0;k<64;k++) acc += x[e*64+k]*Ww[k*64+lane];
  ws[WS_W + e*64 + lane] = acc*0.125f;
  if(lane==0){
    float* Yp = ws + WS_Y + e*16;
    Yp[0]=1.0f;
    Yp[1]=y1v[0]; Yp[2]=y1v[1]; Yp[3]=y1v[2];
    Yp[4]=y2[0]; Yp[5]=y2[1]; Yp[6]=y2[2]; Yp[7]=y2[3]; Yp[8]=y2[4];
    Yp[9]=y3[0]; Yp[10]=y3[1]; Yp[11]=y3[2]; Yp[12]=y3[3]; Yp[13]=y3[4]; Yp[15]=y3[6]; Yp[14]=y3[5];
  }
}

// per node: A[n][m][k] = eps * sum_e w[e][m]*Y[e][k]
__global__ __launch_bounds__(64) void k_node_acc(
    const float* __restrict__ ws_w, const float* __restrict__ ws_y,
    const int* __restrict__ sorted, const int* __restrict__ off, const int* __restrict__ cnt,
    float* __restrict__ A){
  int n = blockIdx.x, m = threadIdx.x;
  float acc[16];
  #pragma unroll
  for(int k=0;k<16;k++) acc[k]=0.f;
  int o = off[n], c = cnt[n];
  for(int j=0;j<c;j++){
    int e = sorted[o+j];
    float wm = ws_w[e*64+m];
    const float* Yp = ws_y + e*16;
    #pragma unroll
    for(int k=0;k<16;k++) acc[k] += wm*Yp[k];
  }
  float4* outp = (float4*)(A + n*1024 + m*16);
  outp[0] = make_float4(acc[0]*0.25f, acc[1]*0.25f, acc[2]*0.25f, acc[3]*0.25f);
  outp[1] = make_float4(acc[4]*0.25f, acc[5]*0.25f, acc[6]*0.25f, acc[7]*0.25f);
  outp[2] = make_float4(acc[8]*0.25f, acc[9]*0.25f, acc[10]*0.25f, acc[11]*0.25f);
  outp[3] = make_float4(acc[12]*0.25f, acc[13]*0.25f, acc[14]*0.25f, acc[15]*0.25f);
}

// main fused kernel: 4 edges per block (sorted order for A-gather locality)
__global__ __launch_bounds__(256) void k_main(
    const float* __restrict__ vectors, const float* __restrict__ x, const float* __restrict__ V,
    const int* __restrict__ senders,
    const float* __restrict__ W1, const float* __restrict__ W2, const float* __restrict__ W3,
    const float* __restrict__ Wl1, const float* __restrict__ Wl2,
    const float* __restrict__ ws, const int* __restrict__ sorted,
    float* __restrict__ out){
  __shared__ float lds_pd[320*33];                    // [v][row], row = eL*8 + c (c<3: P_i w/ Wl1, c>=3: D_{c-3} w/ Wl2)
  __shared__ __align__(16) float lds_wl[2][2048];     // Wl1/Wl2 k-tiles (also MLP h1/h2 scratch)
  __shared__ float lds_h[4*257];                      // h_in = [x | S]
  __shared__ float lds_w3j[573];
  __shared__ float lds_env[4];
  __shared__ int   lds_eid[4];

  int t = threadIdx.x;
  for(int i=t;i<573;i+=256) lds_w3j[i]=ws[i];
  int wv = t>>6, lane = t&63;
  int eid = sorted[blockIdx.x*4 + wv];
  if(lane==0) lds_eid[wv]=eid;
  __syncthreads();

  const float* lw = lds_w3j;
  // ---- phase 1: per-edge (one wave per edge) ----
  {
    float v0=vectors[eid*3], v1=vectors[eid*3+1], v2=vectors[eid*3+2];
    float d = sqrtf(v0*v0+v1*v1+v2*v2);
    float d2=d*d, d4=d2*d2, d6=d4*d2, d7=d6*d, d8=d7*d;
    float env = 1.0f - 28.0f*d6 + 48.0f*d7 - 21.0f*d8;
    env = (d < 1.0f) ? env : 0.0f;
    if(lane==0) lds_env[wv]=env;
  }
  int snd = senders[eid];
  const float4* Ap4 = (const float4*)(ws + WS_A + snd*1024 + lane*16);
  float4 a0=Ap4[0], a1=Ap4[1], a2=Ap4[2], a3=Ap4[3];
  float wY[16] = {a0.x,a0.y,a0.z,a0.w, a1.x,a1.y,a1.z,a1.w,
                  a2.x,a2.y,a2.z,a2.w, a3.x,a3.y,a3.z,a3.w};
  const float* Vp = V + eid*576;
  float V0 = Vp[lane];
  float V1f[3], V2f[5];
  #pragma unroll
  for(int i=0;i<3;i++) V1f[i]=Vp[64+lane*3+i];
  #pragma unroll
  for(int j=0;j<5;j++) V2f[j]=Vp[256+lane*5+j];
  lds_h[wv*257 + lane] = x[eid*64+lane];
  // scalar channel S
  float s0 = wY[0]*V0*lw[O_W000];
  float s1 = 0.f;
  #pragma unroll
  for(int i=0;i<3;i++)
    #pragma unroll
    for(int j=0;j<3;j++) s1 += wY[1+i]*V1f[j]*lw[O_W110 + i*3+j];
  float s2 = 0.f;
  #pragma unroll
  for(int i=0;i<5;i++)
    #pragma unroll
    for(int j=0;j<5;j++) s2 += wY[4+i]*V2f[j]*lw[O_W220 + i*5+j];
  lds_h[wv*257+64+lane]=s0;
  lds_h[wv*257+128+lane]=s1;
  lds_h[wv*257+192+lane]=s2;
  // P paths (l3=1): i=0..2.  D paths (l3=2): j=0..4.
  float P0[3]={0,0,0}, P1[3]={0,0,0}, P2[3]={0,0,0}, P3[3]={0,0,0}, P4[3]={0,0,0};
  float D0[5]={0,0,0,0,0}, D1[5]={0,0,0,0,0}, D2[5]={0,0,0,0,0}, D3[5]={0,0,0,0,0}, D4[5]={0,0,0,0,0};
  #pragma unroll
  for(int b=0;b<3;b++){ float pb=wY[0]*V1f[b];
    #pragma unroll
    for(int i=0;i<3;i++) P0[i]+= pb*lw[O_W011 + b*3+i]; }
  #pragma unroll
  for(int a=0;a<3;a++){ float pa=wY[1+a]*V0;
    #pragma unroll
    for(int i=0;i<3;i++) P1[i]+= pa*lw[O_W101 + a*3+i]; }
  #pragma unroll
  for(int a=0;a<3;a++)
    #pragma unroll
    for(int b=0;b<5;b++){ float p=wY[1+a]*V2f[b];
      #pragma unroll
      for(int i=0;i<3;i++) P2[i]+= p*lw[O_W121 + (a*5+b)*3+i]; }
  #pragma unroll
  for(int a=0;a<5;a++)
    #pragma unroll
    for(int b=0;b<3;b++){ float p=wY[4+a]*V1f[b];
      #pragma unroll
      for(int i=0;i<3;i++) P3[i]+= p*lw[O_W211 + (a*3+b)*3+i]; }
  #pragma unroll
  for(int a=0;a<7;a++)
    #pragma unroll
    for(int b=0;b<5;b++){ float p=wY[9+a]*V2f[b];
      #pragma unroll
      for(int i=0;i<3;i++) P4[i]+= p*lw[O_W321 + (a*5+b)*3+i]; }
  #pragma unroll
  for(int b=0;b<5;b++){ float pb=wY[0]*V2f[b];
    #pragma unroll
    for(int j=0;j<5;j++) D0[j]+= pb*lw[O_W022 + b*5+j]; }
  #pragma unroll
  for(int a=0;a<3;a++)
    #pragma unroll
    for(int b=0;b<3;b++){ float p=wY[1+a]*V1f[b];
      #pragma unroll
      for(int j=0;j<5;j++) D1[j]+= p*lw[O_W112 + (a*3+b)*5+j]; }
  #pragma unroll
  for(int a=0;a<5;a++){ float pa=wY[4+a]*V0;
    #pragma unroll
    for(int j=0;j<5;j++) D2[j]+= pa*lw[O_W202 + a*5+j]; }
  #pragma unroll
  for(int a=0;a<5;a++)
    #pragma unroll
    for(int b=0;b<5;b++){ float p=wY[4+a]*V2f[b];
      #pragma unroll
      for(int j=0;j<5;j++) D3[j]+= p*lw[O_W222 + (a*5+b)*5+j]; }
  #pragma unroll
  for(int a=0;a<7;a++)
    #pragma unroll
    for(int b=0;b<3;b++){ float p=wY[9+a]*V1f[b];
      #pragma unroll
      for(int j=0;j<5;j++) D4[j]+= p*lw[O_W312 + (a*3+b)*5+j]; }
  // stage into lds_pd (fold sqrt(2*l3+1))
  {
    const float SQ3 = 1.7320508075688772f, SQ5 = 2.2360679774997896f;
    int rb = wv*8;
    #pragma unroll
    for(int i=0;i<3;i++){
      lds_pd[(0*64+lane)*33 + rb + i] = SQ3*P0[i];
      lds_pd[(1*64+lane)*33 + rb + i] = SQ3*P1[i];
      lds_pd[(2*64+lane)*33 + rb + i] = SQ3*P2[i];
      lds_pd[(3*64+lane)*33 + rb + i] = SQ3*P3[i];
      lds_pd[(4*64+lane)*33 + rb + i] = SQ3*P4[i];
    }
    #pragma unroll
    for(int j=0;j<5;j++){
      lds_pd[(0*64+lane)*33 + rb + 3+j] = SQ5*D0[j];
      lds_pd[(1*64+lane)*33 + rb + 3+j] = SQ5*D1[j];
      lds_pd[(2*64+lane)*33 + rb + 3+j] = SQ5*D2[j];
      lds_pd[(3*64+lane)*33 + rb + 3+j] = SQ5*D3[j];
      lds_pd[(4*64+lane)*33 + rb + 3+j] = SQ5*D4[j];
    }
  }
  __syncthreads();

  // ---- MLP (block-level; thread = (edge, feature)) ----
  {
    int eL = t>>6, f = t&63;
    float acc=0.f;
    for(int k=0;k<256;k++) acc += lds_h[eL*257+k]*W1[k*64+f];
    acc *= (1.0f/16.0f);
    float h1 = acc/(1.0f+__expf(-acc));
    float* lh1 = &lds_wl[0][0];
    lh1[eL*65+f] = h1;
    __syncthreads();
    acc=0.f;
    for(int k=0;k<64;k++) acc += lh1[eL*65+k]*W2[k*64+f];
    acc *= 0.125f;
    float h2 = acc/(1.0f+__expf(-acc));
    float* lh2 = lh1 + 4*65;
    lh2[eL*65+f] = h2;
    __syncthreads();
    acc=0.f;
    for(int k=0;k<64;k++) acc += lh2[eL*65+k]*W3[k*64+f];
    acc *= 0.125f;
    out[lds_eid[eL]*576 + f] = lds_env[eL]*acc;
  }
  __syncthreads();

  // ---- phase 2: projections V1o/V2e (LDS-tiled, 1 row x 8 cols per thread) ----
  {
    int r = t & 31, cgp = t >> 5;        // row 0..31, col-group 0..7 (8 cols)
    int eL = r>>3, c = r&7;
    float acc[8] = {0,0,0,0,0,0,0,0};
    for(int kt=0; kt<10; kt++){
      const float4* g1 = (const float4*)(Wl1 + kt*2048);
      const float4* g2 = (const float4*)(Wl2 + kt*2048);
      float4* s1p = (float4*)&lds_wl[0][0];
      float4* s2p = (float4*)&lds_wl[1][0];
      s1p[t] = g1[t]; s1p[t+256] = g1[t+256];
      s2p[t] = g2[t]; s2p[t+256] = g2[t+256];
      __syncthreads();
      const float* wlt = (c<3) ? &lds_wl[0][0] : &lds_wl[1][0];
      #pragma unroll
      for(int kk=0;kk<32;kk++){
        float pv = lds_pd[(kt*32+kk)*33 + r];
        const float* wr = wlt + kk*64 + cgp*8;
        float4 wa = *(const float4*)(wr);
        float4 wb = *(const float4*)(wr+4);
        acc[0]+=pv*wa.x; acc[1]+=pv*wa.y; acc[2]+=pv*wa.z; acc[3]+=pv*wa.w;
        acc[4]+=pv*wb.x; acc[5]+=pv*wb.y; acc[6]+=pv*wb.z; acc[7]+=pv*wb.w;
      }
      __syncthreads();
    }
    const float sc = 0.05590169943749474f;  // 1/sqrt(320)
    int eid2 = lds_eid[eL];
    if(c<3){
      #pragma unroll
      for(int uu=0; uu<8; uu++) out[eid2*576 + 64 + (cgp*8+uu)*3 + c] = acc[uu]*sc;
    } else {
      #pragma unroll
      for(int uu=0; uu<8; uu++) out[eid2*576 + 256 + (cgp*8+uu)*5 + (c-3)] = acc[uu]*sc;
    }
  }
}

extern "C" void kernel_launch(void* const* d_in, const int* in_sizes, int n_in,
                              void* d_out, int out_size, void* d_ws, size_t ws_size,
                              hipStream_t stream) {
  const float* vectors=(const float*)d_in[0];
  const float* x      =(const float*)d_in[1];
  const float* V      =(const float*)d_in[2];
  const int*   senders=(const int*)  d_in[3];
  const float* Ww     =(const float*)d_in[4];
  const float* W1     =(const float*)d_in[5];
  const float* W2     =(const float*)d_in[6];
  const float* W3     =(const float*)d_in[7];
  const float* Wl1    =(const float*)d_in[8];
  const float* Wl2    =(const float*)d_in[9];
  float* ws  = (float*)d_ws;
  float* out = (float*)d_out;
  int* cnt    = (int*)(ws + WS_CNT);
  int* off    = (int*)(ws + WS_OFF);
  int* cur    = (int*)(ws + WS_CUR);
  int* sorted = (int*)(ws + WS_SORT);
  float* A    = ws + WS_A;

  k_w3j   <<<14, 128, 0, stream>>>(ws);
  k_c2c3  <<<1, 1, 0, stream>>>(ws);
  k_zero  <<<16, 256, 0, stream>>>(cnt);
  k_count <<<E_EDGES/256, 256, 0, stream>>>(senders, cnt);
  k_scan  <<<1, 1024, 0, stream>>>(cnt, off, cur);
  k_scatter<<<E_EDGES/256, 256, 0, stream>>>(senders, cur, sorted);
  k_edge_pre<<<E_EDGES/4, 256, 0, stream>>>(vectors, x, Ww, ws);
  k_node_acc<<<N_NODES, 64, 0, stream>>>(ws + WS_W, ws + WS_Y, sorted, off, cnt, A);
  k_main  <<<E_EDGES/4, 256, 0, stream>>>(vectors, x, V, senders, W1, W2, W3, Wl1, Wl2,
                                          ws, sorted, out);
}